// Round 8
// baseline (519.162 us; speedup 1.0000x reference)
//
#include <hip/hip_runtime.h>

// ---------------------------------------------------------------------------
// GIN encoder, fp16 feature path + MFMA, fused per-layer kernel (512 thr).
// Aggregation is SOURCE-QUARTILE PHASED: CSR bins are (dst*4 + src_quartile),
// and the layer kernel loops p=0..3 gathering only from src quartile p
// (3.2 MB slice of H -> fits each per-XCD 4MB L2). All resident blocks run
// phases in near-lockstep, so during epoch p the gather working set is
// L2-resident; round 7 profiled 60% of gathers missing to HBM (FETCH 79MB).
// Accumulators for the wave's 8 rows persist in registers across phases.
// Rest of the structure (validated rounds 5-7): gather+BN -> swizzled LDS
// -> GEMM1 -> LDS -> GEMM2 -> Hout + per-block stats; bn_stats reduces;
// last-layer BN folds into pool_proj.
// ---------------------------------------------------------------------------

typedef __attribute__((ext_vector_type(8))) _Float16 f16x8;
typedef __attribute__((ext_vector_type(4))) float f32x4;

static __device__ __forceinline__ float h2f(unsigned short u) {
  return (float)__builtin_bit_cast(_Float16, u);
}
static __device__ __forceinline__ unsigned short f2h(float f) {
  return __builtin_bit_cast(unsigned short, (_Float16)f);
}
static __device__ __forceinline__ float lo16(unsigned int v) { return h2f((unsigned short)(v & 0xffffu)); }
static __device__ __forceinline__ float hi16(unsigned int v) { return h2f((unsigned short)(v >> 16)); }

#define NQ 4  // source quartiles

// ---- CSR build (bins = dst*NQ + src_quartile) ----
__global__ __launch_bounds__(256) void hist_kernel(const int* __restrict__ src,
                                                   const int* __restrict__ dst,
                                                   int* __restrict__ counts, int E, int Q) {
  int e = blockIdx.x * 256 + threadIdx.x;
  if (e < E) {
    int s = src[e], d = dst[e];
    int q = (s >= Q) + (s >= 2 * Q) + (s >= 3 * Q);
    atomicAdd(&counts[d * NQ + q], 1);
  }
}

__global__ __launch_bounds__(512) void scan1_kernel(const int* __restrict__ counts,
                                                    int* __restrict__ incl,
                                                    int* __restrict__ bsums, int n) {
  __shared__ int buf[2][512];
  int t = threadIdx.x;
  int i = blockIdx.x * 512 + t;
  buf[0][t] = (i < n) ? counts[i] : 0;
  __syncthreads();
  int cur = 0;
  for (int off = 1; off < 512; off <<= 1) {
    buf[cur ^ 1][t] = buf[cur][t] + ((t >= off) ? buf[cur][t - off] : 0);
    __syncthreads();
    cur ^= 1;
  }
  if (i < n) incl[i] = buf[cur][t];
  if (t == 511) bsums[blockIdx.x] = buf[cur][511];
}

// exclusive scan of nb (<=512) block sums, in place
__global__ __launch_bounds__(512) void scan2_kernel(int* __restrict__ bsums, int nb) {
  __shared__ int buf[2][512];
  int t = threadIdx.x;
  int v = (t < nb) ? bsums[t] : 0;
  buf[0][t] = v;
  __syncthreads();
  int cur = 0;
  for (int off = 1; off < 512; off <<= 1) {
    buf[cur ^ 1][t] = buf[cur][t] + ((t >= off) ? buf[cur][t - off] : 0);
    __syncthreads();
    cur ^= 1;
  }
  if (t < nb) bsums[t] = buf[cur][t] - v;  // exclusive
}

__global__ __launch_bounds__(256) void scan3_kernel(const int* __restrict__ counts,
                                                    const int* __restrict__ incl,
                                                    const int* __restrict__ bsums,
                                                    int* __restrict__ offsets,
                                                    int* __restrict__ cursor, int n) {
  int i = blockIdx.x * 256 + threadIdx.x;
  if (i < n) {
    int total = bsums[i >> 9] + incl[i];
    offsets[i + 1] = total;
    cursor[i] = total - counts[i];
  }
  if (i == 0) offsets[0] = 0;
}

__global__ __launch_bounds__(256) void fill_kernel(const int* __restrict__ src,
                                                   const int* __restrict__ dst,
                                                   int* cursor, int* __restrict__ srcs, int E,
                                                   int Q) {
  int e = blockIdx.x * 256 + threadIdx.x;
  if (e < E) {
    int s = src[e], d = dst[e];
    int q = (s >= Q) + (s >= 2 * Q) + (s >= 3 * Q);
    int p = atomicAdd(&cursor[d * NQ + q], 1);
    __builtin_nontemporal_store(s, &srcs[p]);
  }
}

// ---- prep: x -> fp16 row-major (uint-packed); zero counts; init affine ----
__global__ __launch_bounds__(256) void prep_kernel(const float* __restrict__ x,
                                                   unsigned int* __restrict__ h,
                                                   int* __restrict__ counts,
                                                   float* __restrict__ scale,
                                                   float* __restrict__ shift, int M) {
  int stride = gridDim.x * 256;
  int tid = blockIdx.x * 256 + threadIdx.x;
  const float2* x2 = (const float2*)x;
  int total = M * 64;
  for (int i = tid; i < total; i += stride) {
    float2 v = x2[i];
    h[i] = (unsigned int)f2h(v.x) | ((unsigned int)f2h(v.y) << 16);
  }
  for (int i = tid; i < M * NQ; i += stride) counts[i] = 0;
  if (tid < 128) { scale[tid] = 1.f; shift[tid] = 0.f; }
}

// WT[m][n][k] = f16(W_m[k][n]), m in [0, 2L): even=W1 layer m/2, odd=W2 layer m/2
__global__ __launch_bounds__(256) void prep_w_kernel(const float* __restrict__ W1,
                                                     const float* __restrict__ W2,
                                                     unsigned short* __restrict__ WT, int total) {
  int idx = blockIdx.x * 256 + threadIdx.x;
  if (idx >= total) return;
  int m = idx >> 14;
  int rem = idx & 16383;
  int n = rem >> 7, k = rem & 127;
  const float* W = ((m & 1) == 0) ? (W1 + (size_t)(m >> 1) * 16384)
                                  : (W2 + (size_t)(m >> 1) * 16384);
  WT[idx] = f2h(W[k * 128 + n]);
}

// ---- fused layer: phased gather+BN -> LDS -> GEMM1 -> LDS -> GEMM2 ----
// LDS tile swizzle: fp16 col c of row rl lives at byte (rl*256 + ((c*2) ^ ((rl&7)<<4))).
// MFMA frag layouts (m89-verified, used in passing rounds 3-7):
//   A/B: lane holds X[(l&15)][ks*32 + (l>>4)*8 + j]; C/D: col=lane&15, row=(lane>>4)*4+reg.
__global__ __launch_bounds__(512, 8) void layer_kernel(
    const unsigned int* __restrict__ Hin,  // M x 64 uints (fp16x2, row-major)
    const int* __restrict__ offsets,       // M*NQ + 1 (bin = r*NQ + q)
    const int* __restrict__ srcs,
    const float* __restrict__ scale, const float* __restrict__ shift,
    const unsigned short* __restrict__ WT1, const float* __restrict__ b1,
    const unsigned short* __restrict__ WT2, const float* __restrict__ b2,
    unsigned short* __restrict__ Hout,  // M x 128 fp16 row-major
    float* __restrict__ pstat, int M) {
  __shared__ unsigned short sT[64 * 128];
  __shared__ float s_sum[128], s_sq[128];
  int t = threadIdx.x;
  if (t < 128) { s_sum[t] = 0.f; s_sq[t] = 0.f; }
  int wave = t >> 6, lane = t & 63;
  int row0 = blockIdx.x * 64;
  char* sTb = (char*)sT;
  float sc0 = scale[2 * lane], sc1 = scale[2 * lane + 1];
  float sh0 = shift[2 * lane], sh1 = shift[2 * lane + 1];

  // ---- phase A: source-quartile-phased gather; wave owns 8 rows ----
  float ax[8], ay[8];
#pragma unroll
  for (int i = 0; i < 8; ++i) {
    int r = row0 + wave * 8 + i;
    if (r < M) {
      unsigned int self = Hin[(size_t)r * 64 + lane];
      ax[i] = lo16(self);
      ay[i] = hi16(self);
    } else {
      ax[i] = 0.f;
      ay[i] = 0.f;
    }
  }
  for (int p = 0; p < NQ; ++p) {  // src-quartile epoch: working set 3.2MB, L2-resident
#pragma unroll
    for (int i = 0; i < 8; ++i) {
      int r = row0 + wave * 8 + i;
      if (r >= M) continue;
      int e0 = offsets[r * NQ + p], e1 = offsets[r * NQ + p + 1];
      for (int base = e0; base < e1; base += 64) {
        int idx = 0;
        if (base + lane < e1) idx = srcs[base + lane];  // masked coalesced idx load
        int cnt = min(64, e1 - base);
        for (int j = 0; j < cnt; j += 4) {
          // 4 independent gathers; lanes >= cnt defaulted to idx=0 (safe), masked out below
          int s0 = __builtin_amdgcn_readlane(idx, j + 0);
          int s1 = __builtin_amdgcn_readlane(idx, j + 1);
          int s2 = __builtin_amdgcn_readlane(idx, j + 2);
          int s3 = __builtin_amdgcn_readlane(idx, j + 3);
          unsigned int v0 = Hin[(size_t)s0 * 64 + lane];
          unsigned int v1 = Hin[(size_t)s1 * 64 + lane];
          unsigned int v2 = Hin[(size_t)s2 * 64 + lane];
          unsigned int v3 = Hin[(size_t)s3 * 64 + lane];
          ax[i] += lo16(v0);
          ay[i] += hi16(v0);
          if (j + 1 < cnt) { ax[i] += lo16(v1); ay[i] += hi16(v1); }
          if (j + 2 < cnt) { ax[i] += lo16(v2); ay[i] += hi16(v2); }
          if (j + 3 < cnt) { ax[i] += lo16(v3); ay[i] += hi16(v3); }
        }
      }
    }
  }
  // BN of previous layer + write swizzled LDS tile
#pragma unroll
  for (int i = 0; i < 8; ++i) {
    int r = row0 + wave * 8 + i;
    int rl_ = wave * 8 + i;
    unsigned int o = 0u;
    if (r < M) {
      int d0 = offsets[r * NQ], d4 = offsets[r * NQ + NQ];
      float d1 = (float)(d4 - d0 + 1);
      o = (unsigned int)f2h(ax[i] * sc0 + d1 * sh0) |
          ((unsigned int)f2h(ay[i] * sc1 + d1 * sh1) << 16);
    }
    *(unsigned int*)(sTb + rl_ * 256 + ((lane * 4) ^ ((rl_ & 7) << 4))) = o;
  }
  __syncthreads();

  // ---- 8-way wave split: wr = row quadrant (16 rows), wc = col half (64) ----
  int wr = wave & 3, wc = wave >> 2;
  int lrow = lane & 15, hi = lane >> 4;
  int lk = hi * 8;
  int rl = wr * 16 + lrow;

  // GEMM1
  f16x8 af[4];
#pragma unroll
  for (int ks = 0; ks < 4; ++ks)
    af[ks] = *(const f16x8*)(sTb + rl * 256 + ((ks * 64 + hi * 16) ^ ((rl & 7) << 4)));
  f32x4 acc[4];
#pragma unroll
  for (int n = 0; n < 4; ++n) acc[n] = (f32x4){0.f, 0.f, 0.f, 0.f};
#pragma unroll
  for (int ks = 0; ks < 4; ++ks) {
    f16x8 bf[4];
#pragma unroll
    for (int n = 0; n < 4; ++n)
      bf[n] = *(const f16x8*)(WT1 + (size_t)(wc * 64 + n * 16 + lrow) * 128 + ks * 32 + lk);
#pragma unroll
    for (int n = 0; n < 4; ++n)
      acc[n] = __builtin_amdgcn_mfma_f32_16x16x32_f16(af[ks], bf[n], acc[n], 0, 0, 0);
  }
  __syncthreads();  // all waves done reading sT before overwrite

  // epilogue1: bias+ReLU -> same LDS tile (swizzled)
#pragma unroll
  for (int n = 0; n < 4; ++n) {
    int col = wc * 64 + n * 16 + lrow;
    float bia = b1[col];
#pragma unroll
    for (int r = 0; r < 4; ++r) {
      int rlw = wr * 16 + hi * 4 + r;
      float v = fmaxf(acc[n][r] + bia, 0.f);
      *(unsigned short*)(sTb + rlw * 256 + ((col * 2) ^ ((rlw & 7) << 4))) = f2h(v);
    }
  }
  __syncthreads();

  // ---- GEMM2 ----
#pragma unroll
  for (int ks = 0; ks < 4; ++ks)
    af[ks] = *(const f16x8*)(sTb + rl * 256 + ((ks * 64 + hi * 16) ^ ((rl & 7) << 4)));
#pragma unroll
  for (int n = 0; n < 4; ++n) acc[n] = (f32x4){0.f, 0.f, 0.f, 0.f};
#pragma unroll
  for (int ks = 0; ks < 4; ++ks) {
    f16x8 bf[4];
#pragma unroll
    for (int n = 0; n < 4; ++n)
      bf[n] = *(const f16x8*)(WT2 + (size_t)(wc * 64 + n * 16 + lrow) * 128 + ks * 32 + lk);
#pragma unroll
    for (int n = 0; n < 4; ++n)
      acc[n] = __builtin_amdgcn_mfma_f32_16x16x32_f16(af[ks], bf[n], acc[n], 0, 0, 0);
  }

  // epilogue2: bias+ReLU -> Hout + per-block column stats (LDS atomics only)
  int rbase = row0 + wr * 16 + hi * 4;
#pragma unroll
  for (int n = 0; n < 4; ++n) {
    int col = wc * 64 + n * 16 + lrow;
    float bia = b2[col];
    float cs = 0.f, cq = 0.f;
#pragma unroll
    for (int r = 0; r < 4; ++r) {
      int rr = rbase + r;
      float v = fmaxf(acc[n][r] + bia, 0.f);
      if (rr < M) {
        Hout[(size_t)rr * 128 + col] = f2h(v);
        cs += v;
        cq += v * v;
      }
    }
    cs += __shfl_xor(cs, 16); cs += __shfl_xor(cs, 32);
    cq += __shfl_xor(cq, 16); cq += __shfl_xor(cq, 32);
    if (hi == 0) {
      atomicAdd(&s_sum[col], cs);
      atomicAdd(&s_sq[col], cq);
    }
  }
  __syncthreads();
  if (t < 128) {
    float* p = pstat + (size_t)blockIdx.x * 256;
    p[t] = s_sum[t];
    p[t + 128] = s_sq[t];
  }
}

// reduce per-block partials -> scale/shift for the next layer (one block per column)
__global__ __launch_bounds__(256) void bn_stats_kernel(const float* __restrict__ pstat, int nb,
                                                       const float* __restrict__ gamma,
                                                       const float* __restrict__ beta,
                                                       float* __restrict__ scale,
                                                       float* __restrict__ shift, float invM) {
  int c = blockIdx.x;
  int t = threadIdx.x;
  float s = 0.f, q = 0.f;
  for (int b = t; b < nb; b += 256) {
    const float* p = pstat + (size_t)b * 256;
    s += p[c];
    q += p[c + 128];
  }
#pragma unroll
  for (int off = 1; off < 64; off <<= 1) {
    s += __shfl_xor(s, off);
    q += __shfl_xor(q, off);
  }
  __shared__ float rs[4], rq[4];
  if ((t & 63) == 0) { rs[t >> 6] = s; rq[t >> 6] = q; }
  __syncthreads();
  if (t == 0) {
    float S = rs[0] + rs[1] + rs[2] + rs[3];
    float Q = rq[0] + rq[1] + rq[2] + rq[3];
    float mean = S * invM;
    float var = fmaxf(Q * invM - mean * mean, 0.f);
    float sc = gamma[c] * rsqrtf(var + 1e-5f);
    scale[c] = sc;
    shift[c] = beta[c] - mean * sc;
  }
}

// ---- fused pool (last layer BN) + projection ----
__global__ __launch_bounds__(256) void pool_proj_kernel(const unsigned int* __restrict__ H,
                                                        const int* __restrict__ batch,
                                                        const float* __restrict__ scale,
                                                        const float* __restrict__ shift,
                                                        const float* __restrict__ Wp,
                                                        const float* __restrict__ bp,
                                                        float* __restrict__ out, int M) {
  int gid = blockIdx.x;
  int lo = 0, hi = M;
  while (lo < hi) { int mid = (lo + hi) >> 1; if (batch[mid] < gid) lo = mid + 1; else hi = mid; }
  int s = lo;
  lo = 0; hi = M;
  while (lo < hi) { int mid = (lo + hi) >> 1; if (batch[mid] < gid + 1) lo = mid + 1; else hi = mid; }
  int e = lo;
  int t = threadIdx.x;
  int cp = t & 63, rs_ = t >> 6;  // col-pair, row phase
  float ax = 0.f, ay = 0.f;
  for (int r = s + rs_; r < e; r += 4) {
    unsigned int v = H[(size_t)r * 64 + cp];
    ax += lo16(v);
    ay += hi16(v);
  }
  __shared__ float redx[256], redy[256];
  __shared__ float g[128];
  redx[t] = ax;
  redy[t] = ay;
  __syncthreads();
  if (t < 128) {
    int cpp = t >> 1;
    float sum;
    if (t & 1)
      sum = redy[cpp] + redy[64 + cpp] + redy[128 + cpp] + redy[192 + cpp];
    else
      sum = redx[cpp] + redx[64 + cpp] + redx[128 + cpp] + redx[192 + cpp];
    g[t] = sum * scale[t] + (float)(e - s) * shift[t];
  }
  __syncthreads();
  if (t < 128) {
    float a2 = bp[t];
#pragma unroll 8
    for (int k = 0; k < 128; ++k) a2 = fmaf(g[k], Wp[k * 128 + t], a2);
    out[gid * 128 + t] = fmaxf(a2, 0.f);
  }
}

extern "C" void kernel_launch(void* const* d_in, const int* in_sizes, int n_in,
                              void* d_out, int out_size, void* d_ws, size_t ws_size,
                              hipStream_t stream) {
  const float* x = (const float*)d_in[0];
  const int* ei = (const int*)d_in[1];
  const int* batch = (const int*)d_in[2];
  const float* W1 = (const float*)d_in[3];
  const float* b1 = (const float*)d_in[4];
  const float* W2 = (const float*)d_in[5];
  const float* b2 = (const float*)d_in[6];
  const float* gamma = (const float*)d_in[7];
  const float* beta = (const float*)d_in[8];
  const float* Wp = (const float*)d_in[9];
  const float* bp = (const float*)d_in[10];
  float* out = (float*)d_out;

  int M = in_sizes[0] / 128;
  int E = in_sizes[1] / 2;
  int L = in_sizes[3] / (128 * 128);
  int G = out_size / 128;
  const int* srcp = ei;
  const int* dstp = ei + E;

  char* w = (char*)d_ws;
  auto alloc = [&](size_t bytes) {
    char* p = w;
    w += (bytes + 255) & ~(size_t)255;
    return p;
  };
  int nblk = (M + 63) / 64;
  int MB = M * NQ;  // bins
  unsigned int* bufA = (unsigned int*)alloc((size_t)M * 64 * 4);
  unsigned int* bufB = (unsigned int*)alloc((size_t)M * 64 * 4);
  unsigned short* WT = (unsigned short*)alloc((size_t)L * 2 * 16384 * 2);
  int* counts = (int*)alloc((size_t)MB * 4);
  int* incl = (int*)alloc((size_t)MB * 4);
  int* bsums = (int*)alloc(512 * 4);
  int* offsets = (int*)alloc((size_t)(MB + 1) * 4);
  int* cursor = (int*)alloc((size_t)MB * 4);
  int* srcs = (int*)alloc((size_t)E * 4);
  float* pstat = (float*)alloc((size_t)nblk * 256 * 4);
  float* stats = (float*)alloc(2 * 128 * 4);
  float* scale = stats;
  float* shift = stats + 128;

  int Q = (M + 3) / 4;
  int nb = (MB + 511) / 512;  // <= 512 for M <= 65536

  prep_kernel<<<2048, 256, 0, stream>>>(x, bufA, counts, scale, shift, M);
  hist_kernel<<<(E + 255) / 256, 256, 0, stream>>>(srcp, dstp, counts, E, Q);
  scan1_kernel<<<nb, 512, 0, stream>>>(counts, incl, bsums, MB);
  scan2_kernel<<<1, 512, 0, stream>>>(bsums, nb);
  scan3_kernel<<<(MB + 255) / 256, 256, 0, stream>>>(counts, incl, bsums, offsets, cursor, MB);
  fill_kernel<<<(E + 255) / 256, 256, 0, stream>>>(srcp, dstp, cursor, srcs, E, Q);
  prep_w_kernel<<<(L * 2 * 16384 + 255) / 256, 256, 0, stream>>>(W1, W2, WT, L * 2 * 16384);

  float invM = 1.0f / (float)M;
  unsigned int* cur = bufA;
  unsigned int* nxt = bufB;
  for (int l = 0; l < L; ++l) {
    layer_kernel<<<nblk, 512, 0, stream>>>(
        cur, offsets, srcs, scale, shift, WT + (size_t)(2 * l) * 16384, b1 + l * 128,
        WT + (size_t)(2 * l + 1) * 16384, b2 + l * 128, (unsigned short*)nxt, pstat, M);
    bn_stats_kernel<<<128, 256, 0, stream>>>(pstat, nblk, gamma + l * 128, beta + l * 128,
                                             scale, shift, invM);
    unsigned int* tmp = cur; cur = nxt; nxt = tmp;
  }

  pool_proj_kernel<<<G, 256, 0, stream>>>(cur, batch, scale, shift, Wp, bp, out, M);
}

// Round 9
// 423.947 us; speedup vs baseline: 1.2246x; 1.2246x over previous
//
#include <hip/hip_runtime.h>

// ---------------------------------------------------------------------------
// GIN encoder, fp16 feature path + MFMA, fused per-layer kernel (512 thr).
// Aggregation locality: each row's CSR edge list is SORTED BY SOURCE (16
// src-bins per row, key = dst*16 + (src>>12)), read contiguously. All blocks
// sweep their lists in near-lockstep, so the gather working set is a moving
// few-MB src window -> per-XCD L2-resident, with round-6's zero-overhead
// gather loop (round 8's explicit per-bin phasing won FETCH but lost 33% to
// bin overhead at ~4 edges/bin).
// Tile = 32 rows/block (1563 blocks): round-6/7 ran 782 blocks = 3/CU which
// GRID-limited occupancy to ~52%; now the 32-waves/CU cap is reachable.
// Rest (validated rounds 5-8): gather+prev-BN -> swizzled LDS -> GEMM1 ->
// LDS -> GEMM2 -> Hout + per-block stats -> bn_stats; last BN in pool_proj.
// ---------------------------------------------------------------------------

typedef __attribute__((ext_vector_type(8))) _Float16 f16x8;
typedef __attribute__((ext_vector_type(4))) float f32x4;

static __device__ __forceinline__ float h2f(unsigned short u) {
  return (float)__builtin_bit_cast(_Float16, u);
}
static __device__ __forceinline__ unsigned short f2h(float f) {
  return __builtin_bit_cast(unsigned short, (_Float16)f);
}
static __device__ __forceinline__ float lo16(unsigned int v) { return h2f((unsigned short)(v & 0xffffu)); }
static __device__ __forceinline__ float hi16(unsigned int v) { return h2f((unsigned short)(v >> 16)); }

#define NB 16     // src bins per row
#define SHIFT 12  // src bin = src >> SHIFT (4096 rows = 1 MB granule)

// ---- CSR build (bins = dst*NB + (src>>SHIFT)) ----
__global__ __launch_bounds__(256) void hist_kernel(const int* __restrict__ src,
                                                   const int* __restrict__ dst,
                                                   int* __restrict__ counts, int E) {
  int e = blockIdx.x * 256 + threadIdx.x;
  if (e < E) {
    int s = src[e], d = dst[e];
    atomicAdd(&counts[d * NB + (s >> SHIFT)], 1);
  }
}

__global__ __launch_bounds__(1024) void scan1_kernel(const int* __restrict__ counts,
                                                     int* __restrict__ incl,
                                                     int* __restrict__ bsums, int n) {
  __shared__ int buf[2][1024];
  int t = threadIdx.x;
  int i = blockIdx.x * 1024 + t;
  buf[0][t] = (i < n) ? counts[i] : 0;
  __syncthreads();
  int cur = 0;
  for (int off = 1; off < 1024; off <<= 1) {
    buf[cur ^ 1][t] = buf[cur][t] + ((t >= off) ? buf[cur][t - off] : 0);
    __syncthreads();
    cur ^= 1;
  }
  if (i < n) incl[i] = buf[cur][t];
  if (t == 1023) bsums[blockIdx.x] = buf[cur][1023];
}

// exclusive scan of nb (<=1024) block sums, in place
__global__ __launch_bounds__(1024) void scan2_kernel(int* __restrict__ bsums, int nb) {
  __shared__ int buf[2][1024];
  int t = threadIdx.x;
  int v = (t < nb) ? bsums[t] : 0;
  buf[0][t] = v;
  __syncthreads();
  int cur = 0;
  for (int off = 1; off < 1024; off <<= 1) {
    buf[cur ^ 1][t] = buf[cur][t] + ((t >= off) ? buf[cur][t - off] : 0);
    __syncthreads();
    cur ^= 1;
  }
  if (t < nb) bsums[t] = buf[cur][t] - v;  // exclusive
}

__global__ __launch_bounds__(256) void scan3_kernel(const int* __restrict__ counts,
                                                    const int* __restrict__ incl,
                                                    const int* __restrict__ bsums,
                                                    int* __restrict__ offsets,
                                                    int* __restrict__ cursor, int n) {
  int i = blockIdx.x * 256 + threadIdx.x;
  if (i < n) {
    int total = bsums[i >> 10] + incl[i];
    offsets[i + 1] = total;
    cursor[i] = total - counts[i];
  }
  if (i == 0) offsets[0] = 0;
}

__global__ __launch_bounds__(256) void fill_kernel(const int* __restrict__ src,
                                                   const int* __restrict__ dst,
                                                   int* cursor, int* __restrict__ srcs, int E) {
  int e = blockIdx.x * 256 + threadIdx.x;
  if (e < E) {
    int s = src[e], d = dst[e];
    int p = atomicAdd(&cursor[d * NB + (s >> SHIFT)], 1);
    __builtin_nontemporal_store(s, &srcs[p]);
  }
}

// ---- prep: x -> fp16 row-major (uint-packed); zero counts; init affine ----
__global__ __launch_bounds__(256) void prep_kernel(const float* __restrict__ x,
                                                   unsigned int* __restrict__ h,
                                                   int* __restrict__ counts,
                                                   float* __restrict__ scale,
                                                   float* __restrict__ shift, int M) {
  int stride = gridDim.x * 256;
  int tid = blockIdx.x * 256 + threadIdx.x;
  const float2* x2 = (const float2*)x;
  int total = M * 64;
  for (int i = tid; i < total; i += stride) {
    float2 v = x2[i];
    h[i] = (unsigned int)f2h(v.x) | ((unsigned int)f2h(v.y) << 16);
  }
  for (int i = tid; i < M * NB; i += stride) counts[i] = 0;
  if (tid < 128) { scale[tid] = 1.f; shift[tid] = 0.f; }
}

// WT[m][n][k] = f16(W_m[k][n]), m in [0, 2L): even=W1 layer m/2, odd=W2 layer m/2
__global__ __launch_bounds__(256) void prep_w_kernel(const float* __restrict__ W1,
                                                     const float* __restrict__ W2,
                                                     unsigned short* __restrict__ WT, int total) {
  int idx = blockIdx.x * 256 + threadIdx.x;
  if (idx >= total) return;
  int m = idx >> 14;
  int rem = idx & 16383;
  int n = rem >> 7, k = rem & 127;
  const float* W = ((m & 1) == 0) ? (W1 + (size_t)(m >> 1) * 16384)
                                  : (W2 + (size_t)(m >> 1) * 16384);
  WT[idx] = f2h(W[k * 128 + n]);
}

// ---- fused layer: gather+BN -> LDS -> GEMM1 -> LDS -> GEMM2 -> Hout+stats ----
// 32-row tile, 8 waves; each wave gathers 4 rows (2 in flight, unroll-4).
// LDS tile swizzle: fp16 col c of row rl lives at byte (rl*256 + ((c*2) ^ ((rl&7)<<4))).
// MFMA frag layouts (m89-verified, rounds 3-8):
//   A/B: lane holds X[(l&15)][ks*32 + (l>>4)*8 + j]; C/D: col=lane&15, row=(lane>>4)*4+reg.
__global__ __launch_bounds__(512, 8) void layer_kernel(
    const unsigned int* __restrict__ Hin,  // M x 64 uints (fp16x2, row-major)
    const int* __restrict__ offsets,       // M*NB + 1 (row r spans [r*NB, r*NB+NB))
    const int* __restrict__ srcs,
    const float* __restrict__ scale, const float* __restrict__ shift,
    const unsigned short* __restrict__ WT1, const float* __restrict__ b1,
    const unsigned short* __restrict__ WT2, const float* __restrict__ b2,
    unsigned short* __restrict__ Hout,  // M x 128 fp16 row-major
    float* __restrict__ pstat, int M) {
  __shared__ unsigned short sT[32 * 128];
  __shared__ float s_sum[128], s_sq[128];
  int t = threadIdx.x;
  if (t < 128) { s_sum[t] = 0.f; s_sq[t] = 0.f; }
  int wave = t >> 6, lane = t & 63;
  int row0 = blockIdx.x * 32;
  char* sTb = (char*)sT;
  float sc0 = scale[2 * lane], sc1 = scale[2 * lane + 1];
  float sh0 = shift[2 * lane], sh1 = shift[2 * lane + 1];

  // ---- phase A: gather (src-sorted contiguous lists) + prev-layer BN ----
  for (int i = 0; i < 4; i += 2) {
    int rA = row0 + wave * 4 + i;
    int rB = rA + 1;
    float axA = 0.f, ayA = 0.f, axB = 0.f, ayB = 0.f;
    int eA = 0, eA1 = 0, eB = 0, eB1 = 0;
    if (rA < M) {
      eA = offsets[rA * NB]; eA1 = offsets[rA * NB + NB];
      unsigned int s = Hin[(size_t)rA * 64 + lane];
      axA = lo16(s); ayA = hi16(s);
    }
    if (rB < M) {
      eB = offsets[rB * NB]; eB1 = offsets[rB * NB + NB];
      unsigned int s = Hin[(size_t)rB * 64 + lane];
      axB = lo16(s); ayB = hi16(s);
    }
    int dA = eA1 - eA, dB = eB1 - eB;
    while (eA + 4 <= eA1 && eB + 4 <= eB1) {
      int a0 = srcs[eA], a1 = srcs[eA + 1], a2 = srcs[eA + 2], a3 = srcs[eA + 3];
      int c0 = srcs[eB], c1 = srcs[eB + 1], c2 = srcs[eB + 2], c3 = srcs[eB + 3];
      unsigned int vA0 = Hin[(size_t)a0 * 64 + lane];
      unsigned int vA1 = Hin[(size_t)a1 * 64 + lane];
      unsigned int vA2 = Hin[(size_t)a2 * 64 + lane];
      unsigned int vA3 = Hin[(size_t)a3 * 64 + lane];
      unsigned int vB0 = Hin[(size_t)c0 * 64 + lane];
      unsigned int vB1 = Hin[(size_t)c1 * 64 + lane];
      unsigned int vB2 = Hin[(size_t)c2 * 64 + lane];
      unsigned int vB3 = Hin[(size_t)c3 * 64 + lane];
      axA += lo16(vA0) + lo16(vA1) + lo16(vA2) + lo16(vA3);
      ayA += hi16(vA0) + hi16(vA1) + hi16(vA2) + hi16(vA3);
      axB += lo16(vB0) + lo16(vB1) + lo16(vB2) + lo16(vB3);
      ayB += hi16(vB0) + hi16(vB1) + hi16(vB2) + hi16(vB3);
      eA += 4; eB += 4;
    }
    while (eA + 4 <= eA1) {
      int a0 = srcs[eA], a1 = srcs[eA + 1], a2 = srcs[eA + 2], a3 = srcs[eA + 3];
      unsigned int v0 = Hin[(size_t)a0 * 64 + lane];
      unsigned int v1 = Hin[(size_t)a1 * 64 + lane];
      unsigned int v2 = Hin[(size_t)a2 * 64 + lane];
      unsigned int v3 = Hin[(size_t)a3 * 64 + lane];
      axA += lo16(v0) + lo16(v1) + lo16(v2) + lo16(v3);
      ayA += hi16(v0) + hi16(v1) + hi16(v2) + hi16(v3);
      eA += 4;
    }
    while (eB + 4 <= eB1) {
      int c0 = srcs[eB], c1 = srcs[eB + 1], c2 = srcs[eB + 2], c3 = srcs[eB + 3];
      unsigned int v0 = Hin[(size_t)c0 * 64 + lane];
      unsigned int v1 = Hin[(size_t)c1 * 64 + lane];
      unsigned int v2 = Hin[(size_t)c2 * 64 + lane];
      unsigned int v3 = Hin[(size_t)c3 * 64 + lane];
      axB += lo16(v0) + lo16(v1) + lo16(v2) + lo16(v3);
      ayB += hi16(v0) + hi16(v1) + hi16(v2) + hi16(v3);
      eB += 4;
    }
    for (; eA < eA1; ++eA) {
      unsigned int v = Hin[(size_t)srcs[eA] * 64 + lane];
      axA += lo16(v); ayA += hi16(v);
    }
    for (; eB < eB1; ++eB) {
      unsigned int v = Hin[(size_t)srcs[eB] * 64 + lane];
      axB += lo16(v); ayB += hi16(v);
    }
    int rlA = wave * 4 + i, rlB = rlA + 1;
    float dA1 = (float)(dA + 1), dB1 = (float)(dB + 1);
    unsigned int oA = (unsigned int)f2h(axA * sc0 + dA1 * sh0) |
                      ((unsigned int)f2h(ayA * sc1 + dA1 * sh1) << 16);
    unsigned int oB = (unsigned int)f2h(axB * sc0 + dB1 * sh0) |
                      ((unsigned int)f2h(ayB * sc1 + dB1 * sh1) << 16);
    *(unsigned int*)(sTb + rlA * 256 + ((lane * 4) ^ ((rlA & 7) << 4))) = (rA < M) ? oA : 0u;
    *(unsigned int*)(sTb + rlB * 256 + ((lane * 4) ^ ((rlB & 7) << 4))) = (rB < M) ? oB : 0u;
  }
  __syncthreads();

  // ---- 8-way wave split: wr = row half (16 rows), wc = col quarter (32) ----
  int wr = wave & 1, wc = wave >> 1;
  int lrow = lane & 15, hi = lane >> 4;
  int lk = hi * 8;
  int rl = wr * 16 + lrow;

  // GEMM1
  f16x8 af[4];
#pragma unroll
  for (int ks = 0; ks < 4; ++ks)
    af[ks] = *(const f16x8*)(sTb + rl * 256 + ((ks * 64 + hi * 16) ^ ((rl & 7) << 4)));
  f32x4 acc[2];
#pragma unroll
  for (int n = 0; n < 2; ++n) acc[n] = (f32x4){0.f, 0.f, 0.f, 0.f};
#pragma unroll
  for (int ks = 0; ks < 4; ++ks) {
    f16x8 bf[2];
#pragma unroll
    for (int n = 0; n < 2; ++n)
      bf[n] = *(const f16x8*)(WT1 + (size_t)(wc * 32 + n * 16 + lrow) * 128 + ks * 32 + lk);
#pragma unroll
    for (int n = 0; n < 2; ++n)
      acc[n] = __builtin_amdgcn_mfma_f32_16x16x32_f16(af[ks], bf[n], acc[n], 0, 0, 0);
  }
  __syncthreads();  // all waves done reading sT before overwrite

  // epilogue1: bias+ReLU -> same LDS tile (swizzled)
#pragma unroll
  for (int n = 0; n < 2; ++n) {
    int col = wc * 32 + n * 16 + lrow;
    float bia = b1[col];
#pragma unroll
    for (int r = 0; r < 4; ++r) {
      int rlw = wr * 16 + hi * 4 + r;
      float v = fmaxf(acc[n][r] + bia, 0.f);
      *(unsigned short*)(sTb + rlw * 256 + ((col * 2) ^ ((rlw & 7) << 4))) = f2h(v);
    }
  }
  __syncthreads();

  // ---- GEMM2 ----
#pragma unroll
  for (int ks = 0; ks < 4; ++ks)
    af[ks] = *(const f16x8*)(sTb + rl * 256 + ((ks * 64 + hi * 16) ^ ((rl & 7) << 4)));
#pragma unroll
  for (int n = 0; n < 2; ++n) acc[n] = (f32x4){0.f, 0.f, 0.f, 0.f};
#pragma unroll
  for (int ks = 0; ks < 4; ++ks) {
    f16x8 bf[2];
#pragma unroll
    for (int n = 0; n < 2; ++n)
      bf[n] = *(const f16x8*)(WT2 + (size_t)(wc * 32 + n * 16 + lrow) * 128 + ks * 32 + lk);
#pragma unroll
    for (int n = 0; n < 2; ++n)
      acc[n] = __builtin_amdgcn_mfma_f32_16x16x32_f16(af[ks], bf[n], acc[n], 0, 0, 0);
  }

  // epilogue2: bias+ReLU -> Hout + per-block column stats (LDS atomics only)
  int rbase = row0 + wr * 16 + hi * 4;
#pragma unroll
  for (int n = 0; n < 2; ++n) {
    int col = wc * 32 + n * 16 + lrow;
    float bia = b2[col];
    float cs = 0.f, cq = 0.f;
#pragma unroll
    for (int r = 0; r < 4; ++r) {
      int rr = rbase + r;
      float v = fmaxf(acc[n][r] + bia, 0.f);
      if (rr < M) {
        Hout[(size_t)rr * 128 + col] = f2h(v);
        cs += v;
        cq += v * v;
      }
    }
    cs += __shfl_xor(cs, 16); cs += __shfl_xor(cs, 32);
    cq += __shfl_xor(cq, 16); cq += __shfl_xor(cq, 32);
    if (hi == 0) {
      atomicAdd(&s_sum[col], cs);
      atomicAdd(&s_sq[col], cq);
    }
  }
  __syncthreads();
  if (t < 128) {
    float* p = pstat + (size_t)blockIdx.x * 256;
    p[t] = s_sum[t];
    p[t + 128] = s_sq[t];
  }
}

// reduce per-block partials -> scale/shift for the next layer (one block per column)
__global__ __launch_bounds__(256) void bn_stats_kernel(const float* __restrict__ pstat, int nb,
                                                       const float* __restrict__ gamma,
                                                       const float* __restrict__ beta,
                                                       float* __restrict__ scale,
                                                       float* __restrict__ shift, float invM) {
  int c = blockIdx.x;
  int t = threadIdx.x;
  float s = 0.f, q = 0.f;
  for (int b = t; b < nb; b += 256) {
    const float* p = pstat + (size_t)b * 256;
    s += p[c];
    q += p[c + 128];
  }
#pragma unroll
  for (int off = 1; off < 64; off <<= 1) {
    s += __shfl_xor(s, off);
    q += __shfl_xor(q, off);
  }
  __shared__ float rs[4], rq[4];
  if ((t & 63) == 0) { rs[t >> 6] = s; rq[t >> 6] = q; }
  __syncthreads();
  if (t == 0) {
    float S = rs[0] + rs[1] + rs[2] + rs[3];
    float Q = rq[0] + rq[1] + rq[2] + rq[3];
    float mean = S * invM;
    float var = fmaxf(Q * invM - mean * mean, 0.f);
    float sc = gamma[c] * rsqrtf(var + 1e-5f);
    scale[c] = sc;
    shift[c] = beta[c] - mean * sc;
  }
}

// ---- fused pool (last layer BN) + projection ----
__global__ __launch_bounds__(256) void pool_proj_kernel(const unsigned int* __restrict__ H,
                                                        const int* __restrict__ batch,
                                                        const float* __restrict__ scale,
                                                        const float* __restrict__ shift,
                                                        const float* __restrict__ Wp,
                                                        const float* __restrict__ bp,
                                                        float* __restrict__ out, int M) {
  int gid = blockIdx.x;
  int lo = 0, hi = M;
  while (lo < hi) { int mid = (lo + hi) >> 1; if (batch[mid] < gid) lo = mid + 1; else hi = mid; }
  int s = lo;
  lo = 0; hi = M;
  while (lo < hi) { int mid = (lo + hi) >> 1; if (batch[mid] < gid + 1) lo = mid + 1; else hi = mid; }
  int e = lo;
  int t = threadIdx.x;
  int cp = t & 63, rs_ = t >> 6;  // col-pair, row phase
  float ax = 0.f, ay = 0.f;
  for (int r = s + rs_; r < e; r += 4) {
    unsigned int v = H[(size_t)r * 64 + cp];
    ax += lo16(v);
    ay += hi16(v);
  }
  __shared__ float redx[256], redy[256];
  __shared__ float g[128];
  redx[t] = ax;
  redy[t] = ay;
  __syncthreads();
  if (t < 128) {
    int cpp = t >> 1;
    float sum;
    if (t & 1)
      sum = redy[cpp] + redy[64 + cpp] + redy[128 + cpp] + redy[192 + cpp];
    else
      sum = redx[cpp] + redx[64 + cpp] + redx[128 + cpp] + redx[192 + cpp];
    g[t] = sum * scale[t] + (float)(e - s) * shift[t];
  }
  __syncthreads();
  if (t < 128) {
    float a2 = bp[t];
#pragma unroll 8
    for (int k = 0; k < 128; ++k) a2 = fmaf(g[k], Wp[k * 128 + t], a2);
    out[gid * 128 + t] = fmaxf(a2, 0.f);
  }
}

extern "C" void kernel_launch(void* const* d_in, const int* in_sizes, int n_in,
                              void* d_out, int out_size, void* d_ws, size_t ws_size,
                              hipStream_t stream) {
  const float* x = (const float*)d_in[0];
  const int* ei = (const int*)d_in[1];
  const int* batch = (const int*)d_in[2];
  const float* W1 = (const float*)d_in[3];
  const float* b1 = (const float*)d_in[4];
  const float* W2 = (const float*)d_in[5];
  const float* b2 = (const float*)d_in[6];
  const float* gamma = (const float*)d_in[7];
  const float* beta = (const float*)d_in[8];
  const float* Wp = (const float*)d_in[9];
  const float* bp = (const float*)d_in[10];
  float* out = (float*)d_out;

  int M = in_sizes[0] / 128;
  int E = in_sizes[1] / 2;
  int L = in_sizes[3] / (128 * 128);
  int G = out_size / 128;
  const int* srcp = ei;
  const int* dstp = ei + E;

  char* w = (char*)d_ws;
  auto alloc = [&](size_t bytes) {
    char* p = w;
    w += (bytes + 255) & ~(size_t)255;
    return p;
  };
  int nblk = (M + 31) / 32;
  int MB = M * NB;  // bins
  size_t binbytes = (size_t)MB * 4;
  size_t ebytes = (size_t)E * 4;
  unsigned int* bufA = (unsigned int*)alloc((size_t)M * 64 * 4);
  unsigned int* bufB = (unsigned int*)alloc((size_t)M * 64 * 4);
  unsigned short* WT = (unsigned short*)alloc((size_t)L * 2 * 16384 * 2);
  // regionA: counts+incl during CSR build; reused as srcs afterwards
  char* regionA = alloc(2 * binbytes > ebytes ? 2 * binbytes : ebytes);
  int* counts = (int*)regionA;
  int* incl = (int*)(regionA + binbytes);
  int* srcs = (int*)regionA;  // aliases counts/incl (dead after scan3)
  int* bsums = (int*)alloc(1024 * 4);
  int* offsets = (int*)alloc(binbytes + 256);
  int* cursor = (int*)alloc(binbytes);
  float* pstat = (float*)alloc((size_t)nblk * 256 * 4);
  float* stats = (float*)alloc(2 * 128 * 4);
  float* scale = stats;
  float* shift = stats + 128;

  int nb1 = (MB + 1023) / 1024;  // <= 1024 for M <= 65536

  prep_kernel<<<2048, 256, 0, stream>>>(x, bufA, counts, scale, shift, M);
  hist_kernel<<<(E + 255) / 256, 256, 0, stream>>>(srcp, dstp, counts, E);
  scan1_kernel<<<nb1, 1024, 0, stream>>>(counts, incl, bsums, MB);
  scan2_kernel<<<1, 1024, 0, stream>>>(bsums, nb1);
  scan3_kernel<<<(MB + 255) / 256, 256, 0, stream>>>(counts, incl, bsums, offsets, cursor, MB);
  fill_kernel<<<(E + 255) / 256, 256, 0, stream>>>(srcp, dstp, cursor, srcs, E);
  prep_w_kernel<<<(L * 2 * 16384 + 255) / 256, 256, 0, stream>>>(W1, W2, WT, L * 2 * 16384);

  float invM = 1.0f / (float)M;
  unsigned int* cur = bufA;
  unsigned int* nxt = bufB;
  for (int l = 0; l < L; ++l) {
    layer_kernel<<<nblk, 512, 0, stream>>>(
        cur, offsets, srcs, scale, shift, WT + (size_t)(2 * l) * 16384, b1 + l * 128,
        WT + (size_t)(2 * l + 1) * 16384, b2 + l * 128, (unsigned short*)nxt, pstat, M);
    bn_stats_kernel<<<128, 256, 0, stream>>>(pstat, nblk, gamma + l * 128, beta + l * 128,
                                             scale, shift, invM);
    unsigned int* tmp = cur; cur = nxt; nxt = tmp;
  }

  pool_proj_kernel<<<G, 256, 0, stream>>>(cur, batch, scale, shift, Wp, bp, out, M);
}